// Round 2
// baseline (136.855 us; speedup 1.0000x reference)
//
#include <hip/hip_runtime.h>
#include <hip/hip_bf16.h>
#include <math.h>

#define B_ 2
#define N_ 2048
#define D_ 512
#define H_ 8
#define DK_ 64
#define M_ (B_ * N_)  // 4096

typedef short s16x8 __attribute__((ext_vector_type(8)));
typedef short s16x4 __attribute__((ext_vector_type(4)));
typedef float fx4   __attribute__((ext_vector_type(4)));
typedef int   ix4   __attribute__((ext_vector_type(4)));

static __device__ __forceinline__ short f2bf(float f) {
    __hip_bfloat16 h = __float2bfloat16(f);
    return __builtin_bit_cast(short, h);
}
static __device__ __forceinline__ float bf2f(short s) {
    unsigned int u = ((unsigned int)(unsigned short)s) << 16;
    return __builtin_bit_cast(float, u);
}
static __device__ __forceinline__ float fexp2(float x) {
#if __has_builtin(__builtin_amdgcn_exp2f)
    return __builtin_amdgcn_exp2f(x);
#else
    return exp2f(x);
#endif
}
static __device__ __forceinline__ float fsqrt_(float x) {
#if __has_builtin(__builtin_amdgcn_sqrtf)
    return __builtin_amdgcn_sqrtf(x);
#else
    return sqrtf(x);
#endif
}
// pack two f32 into bf16x2 by truncation (valid for p >= 0): lo = a, hi = b.
static __device__ __forceinline__ int pack_tr(float a, float b) {
    unsigned ua = __builtin_bit_cast(unsigned, a);
    unsigned ub = __builtin_bit_cast(unsigned, b);
    return (int)((ua >> 16) | (ub & 0xFFFF0000u));
}

#define MFMA16(a, b, c) __builtin_amdgcn_mfma_f32_16x16x32_bf16(a, b, c, 0, 0, 0)

// log2-units score scale: 0.125 * log2(e); fixed softmax shift M0 (shift-invariant)
#define C2_ 0.18033688f
#define M0_ 16.0f

// ---------------------------------------------------------------------------
// Q+K projection (one dispatch, z selects weights/outputs). bf16 MFMA.
// Tile 128x64, BK=32, 4 waves (2x2). T14 reg-staged prefetch, incremental addr.
// ---------------------------------------------------------------------------
__global__ __launch_bounds__(256, 2)
void qkproj_mfma(const float* __restrict__ xr, const float* __restrict__ xi,
                 const float* __restrict__ W0r, const float* __restrict__ W0i,
                 const float* __restrict__ b0r, const float* __restrict__ b0i,
                 const float* __restrict__ W1r, const float* __restrict__ W1i,
                 const float* __restrict__ b1r, const float* __restrict__ b1i,
                 short* __restrict__ o0r, short* __restrict__ o0i,
                 short* __restrict__ o1r, short* __restrict__ o1i)
{
    __shared__ short sA[2][128][40];
    __shared__ short sB[2][64][40];

    const int tid = threadIdx.x;
    const int w = tid >> 6, l = tid & 63, lg = l >> 4, lc = l & 15;
    const int wr = w >> 1, wc = w & 1;
    const int bn = blockIdx.x, bm = blockIdx.y, z = blockIdx.z;
    const float* Wr = z ? W1r : W0r;
    const float* Wi = z ? W1i : W0i;
    const float* br = z ? b1r : b0r;
    const float* bi = z ? b1i : b0i;
    short* outr = z ? o1r : o0r;
    short* outi = z ? o1i : o0i;

    const int srow = tid >> 3, scol = (tid & 7) * 4;
    int aoff = (bm * 128 + srow) * D_ + scol;   // += 32 per k-step
    int boff = (bn * 64 + srow) * D_ + scol;

    float4 rA[8], rB[4];
    auto issue = [&]() {
#pragma unroll
        for (int u = 0; u < 8; ++u) {
            const float* src = (u >= 4) ? xi : xr;
            rA[u] = *(const float4*)&src[aoff + (u & 3) * 32 * D_];
        }
#pragma unroll
        for (int u = 0; u < 4; ++u) {
            const float* src = (u >= 2) ? Wi : Wr;
            rB[u] = *(const float4*)&src[boff + (u & 1) * 32 * D_];
        }
        aoff += 32; boff += 32;
    };

    fx4 Cre[4][2], Cim[4][2];
#pragma unroll
    for (int mf = 0; mf < 4; ++mf)
#pragma unroll
        for (int nf = 0; nf < 2; ++nf)
#pragma unroll
            for (int j = 0; j < 4; ++j) { Cre[mf][nf][j] = 0.f; Cim[mf][nf][j] = 0.f; }

    issue();
    for (int k0 = 0; k0 < D_; k0 += 32) {
        __syncthreads();
#pragma unroll
        for (int u = 0; u < 8; ++u) {
            int comp = u >> 2, row = (u & 3) * 32 + srow;
            float vv[4] = {rA[u].x, rA[u].y, rA[u].z, rA[u].w};
            s16x4 hv;
#pragma unroll
            for (int q = 0; q < 4; ++q) hv[q] = f2bf(vv[q]);
            *(s16x4*)&sA[comp][row][scol] = hv;
        }
#pragma unroll
        for (int u = 0; u < 4; ++u) {
            int comp = u >> 1, row = (u & 1) * 32 + srow;
            float vv[4] = {rB[u].x, rB[u].y, rB[u].z, rB[u].w};
            s16x4 hv;
#pragma unroll
            for (int q = 0; q < 4; ++q) hv[q] = f2bf(vv[q]);
            *(s16x4*)&sB[comp][row][scol] = hv;
        }
        __syncthreads();
        if (k0 + 32 < D_) issue();

        s16x8 a[2][4];
#pragma unroll
        for (int comp = 0; comp < 2; ++comp)
#pragma unroll
            for (int mf = 0; mf < 4; ++mf)
                a[comp][mf] = *(const s16x8*)&sA[comp][wr * 64 + mf * 16 + lc][lg * 8];
        s16x8 bfr[2][2], bin[2];
#pragma unroll
        for (int comp = 0; comp < 2; ++comp)
#pragma unroll
            for (int nf = 0; nf < 2; ++nf)
                bfr[comp][nf] = *(const s16x8*)&sB[comp][wc * 32 + nf * 16 + lc][lg * 8];
#pragma unroll
        for (int nf = 0; nf < 2; ++nf) bin[nf] = bfr[1][nf] ^ (short)0x8000;

        __builtin_amdgcn_s_setprio(1);
#pragma unroll
        for (int mf = 0; mf < 4; ++mf)
#pragma unroll
            for (int nf = 0; nf < 2; ++nf) {
                Cre[mf][nf] = MFMA16(a[0][mf], bfr[0][nf], Cre[mf][nf]);
                Cre[mf][nf] = MFMA16(a[1][mf], bin[nf],    Cre[mf][nf]);
                Cim[mf][nf] = MFMA16(a[0][mf], bfr[1][nf], Cim[mf][nf]);
                Cim[mf][nf] = MFMA16(a[1][mf], bfr[0][nf], Cim[mf][nf]);
            }
        __builtin_amdgcn_s_setprio(0);
    }

    const int bb = (bm * 128) >> 11;
#pragma unroll
    for (int nf = 0; nf < 2; ++nf) {
        const int c = bn * 64 + wc * 32 + nf * 16 + lc;
        const float brv = br[c], biv = bi[c];
        const int h = c >> 6, dd = c & 63;
        const int n00 = (bm * 128 + wr * 64 + lg * 4) & (N_ - 1);
        size_t obase = (((size_t)(bb * H_ + h) * N_) + n00) * DK_ + dd;
#pragma unroll
        for (int mf = 0; mf < 4; ++mf)
#pragma unroll
            for (int j = 0; j < 4; ++j) {
                size_t o = obase + (size_t)(mf * 16 + j) * DK_;
                outr[o] = f2bf(Cre[mf][nf][j] + brv);
                outi[o] = f2bf(Cim[mf][nf][j] + biv);
            }
    }
}

// ---------------------------------------------------------------------------
// V projection: 3-term bf16 split (hi/lo), transposed output [bh][dk][n].
// BM=64 (grid 512 -> 2 blocks/CU). Wave tile 32x32.
// ---------------------------------------------------------------------------
__global__ __launch_bounds__(256, 2)
void vproj_mfma(const float* __restrict__ xr, const float* __restrict__ xi,
                const float* __restrict__ Wr, const float* __restrict__ Wi,
                const float* __restrict__ br, const float* __restrict__ bi,
                short* __restrict__ outr, short* __restrict__ outi)
{
    __shared__ short sA[2][2][64][40];
    __shared__ short sB[2][2][64][40];

    const int tid = threadIdx.x;
    const int w = tid >> 6, l = tid & 63, lg = l >> 4, lc = l & 15;
    const int wr = w >> 1, wc = w & 1;
    const int bn = blockIdx.x, bm = blockIdx.y;

    const int srow = tid >> 3, scol = (tid & 7) * 4;
    int aoff = (bm * 64 + srow) * D_ + scol;
    int boff = (bn * 64 + srow) * D_ + scol;

    float4 rA[4], rB[4];
    auto issue = [&]() {
#pragma unroll
        for (int u = 0; u < 4; ++u) {
            const float* src = (u >= 2) ? xi : xr;
            rA[u] = *(const float4*)&src[aoff + (u & 1) * 32 * D_];
        }
#pragma unroll
        for (int u = 0; u < 4; ++u) {
            const float* src = (u >= 2) ? Wi : Wr;
            rB[u] = *(const float4*)&src[boff + (u & 1) * 32 * D_];
        }
        aoff += 32; boff += 32;
    };

    fx4 Cre[2][2], Cim[2][2];
#pragma unroll
    for (int mf = 0; mf < 2; ++mf)
#pragma unroll
        for (int nf = 0; nf < 2; ++nf)
#pragma unroll
            for (int j = 0; j < 4; ++j) { Cre[mf][nf][j] = 0.f; Cim[mf][nf][j] = 0.f; }

    issue();
    for (int k0 = 0; k0 < D_; k0 += 32) {
        __syncthreads();
#pragma unroll
        for (int u = 0; u < 4; ++u) {
            int comp = u >> 1, row = (u & 1) * 32 + srow;
            float vv[4] = {rA[u].x, rA[u].y, rA[u].z, rA[u].w};
            s16x4 hv, lv;
#pragma unroll
            for (int q = 0; q < 4; ++q) {
                short hh = f2bf(vv[q]);
                hv[q] = hh;
                lv[q] = f2bf(vv[q] - bf2f(hh));
            }
            *(s16x4*)&sA[comp][0][row][scol] = hv;
            *(s16x4*)&sA[comp][1][row][scol] = lv;
        }
#pragma unroll
        for (int u = 0; u < 4; ++u) {
            int comp = u >> 1, row = (u & 1) * 32 + srow;
            float vv[4] = {rB[u].x, rB[u].y, rB[u].z, rB[u].w};
            s16x4 hv, lv;
#pragma unroll
            for (int q = 0; q < 4; ++q) {
                short hh = f2bf(vv[q]);
                hv[q] = hh;
                lv[q] = f2bf(vv[q] - bf2f(hh));
            }
            *(s16x4*)&sB[comp][0][row][scol] = hv;
            *(s16x4*)&sB[comp][1][row][scol] = lv;
        }
        __syncthreads();
        if (k0 + 32 < D_) issue();

        s16x8 a[2][2][2];
#pragma unroll
        for (int comp = 0; comp < 2; ++comp)
#pragma unroll
            for (int s = 0; s < 2; ++s)
#pragma unroll
                for (int mf = 0; mf < 2; ++mf)
                    a[comp][s][mf] = *(const s16x8*)&sA[comp][s][wr * 32 + mf * 16 + lc][lg * 8];
        s16x8 bfr[2][2][2], bin[2][2];
#pragma unroll
        for (int comp = 0; comp < 2; ++comp)
#pragma unroll
            for (int s = 0; s < 2; ++s)
#pragma unroll
                for (int nf = 0; nf < 2; ++nf)
                    bfr[comp][s][nf] = *(const s16x8*)&sB[comp][s][wc * 32 + nf * 16 + lc][lg * 8];
#pragma unroll
        for (int s = 0; s < 2; ++s)
#pragma unroll
            for (int nf = 0; nf < 2; ++nf)
                bin[s][nf] = bfr[1][s][nf] ^ (short)0x8000;

        __builtin_amdgcn_s_setprio(1);
#pragma unroll
        for (int mf = 0; mf < 2; ++mf)
#pragma unroll
            for (int nf = 0; nf < 2; ++nf) {
                fx4 cr = Cre[mf][nf], ci = Cim[mf][nf];
                cr = MFMA16(a[0][0][mf], bfr[0][0][nf], cr);
                cr = MFMA16(a[1][0][mf], bin[0][nf],    cr);
                ci = MFMA16(a[0][0][mf], bfr[1][0][nf], ci);
                ci = MFMA16(a[1][0][mf], bfr[0][0][nf], ci);
                cr = MFMA16(a[0][0][mf], bfr[0][1][nf], cr);
                cr = MFMA16(a[0][1][mf], bfr[0][0][nf], cr);
                cr = MFMA16(a[1][0][mf], bin[1][nf],    cr);
                cr = MFMA16(a[1][1][mf], bin[0][nf],    cr);
                ci = MFMA16(a[0][0][mf], bfr[1][1][nf], ci);
                ci = MFMA16(a[0][1][mf], bfr[1][0][nf], ci);
                ci = MFMA16(a[1][0][mf], bfr[0][1][nf], ci);
                ci = MFMA16(a[1][1][mf], bfr[0][0][nf], ci);
                Cre[mf][nf] = cr; Cim[mf][nf] = ci;
            }
        __builtin_amdgcn_s_setprio(0);
    }

    const int bb = (bm * 64) >> 11;
#pragma unroll
    for (int nf = 0; nf < 2; ++nf) {
        const int c = bn * 64 + wc * 32 + nf * 16 + lc;
        const float brv = br[c], biv = bi[c];
        const int h = c >> 6, dd = c & 63;
#pragma unroll
        for (int mf = 0; mf < 2; ++mf) {
            int m0 = bm * 64 + wr * 32 + mf * 16 + lg * 4;
            int n0 = m0 & (N_ - 1);
            s16x4 pr, pi;
#pragma unroll
            for (int j = 0; j < 4; ++j) {
                pr[j] = f2bf(Cre[mf][nf][j] + brv);
                pi[j] = f2bf(Cim[mf][nf][j] + biv);
            }
            size_t o = (((size_t)(bb * H_ + h) * DK_) + dd) * N_ + n0;
            *(s16x4*)&outr[o] = pr;
            *(s16x4*)&outi[o] = pi;
        }
    }
}

// ---------------------------------------------------------------------------
// MFMA flash attention, QBLK=128, 4 waves x 32 Q-rows (2 B-fragments each).
// LDS-BW-bound analysis (r1): K/V fragment reads are Q-independent, so
// doubling Q-rows/wave HALVES LDS read traffic per unit work (2.6GB->1.3GB).
// Rotation swizzle slot' = (slot + (row&7) + 2*((row>>3)&3)) & 7 with row
// stride 64 shorts makes writes, QK reads and PV reads all bank-UNIFORM
// (exactly 8 lanes per bank-quad = hw minimum for b128).
// Double-buffered LDS: ONE barrier per iter; staging writes overlap other
// waves' compute. 256 blocks (1/CU), launch_bounds(256,1) frees VGPR cap.
// Swapped QK^T with permuted k-tiles keeps P in registers (no sP).
// XCD remap: 2 bh per XCD -> K/V 2MB resident in that XCD's L2.
// ---------------------------------------------------------------------------
#define NT_ (N_ / 64)

static __device__ __forceinline__ int swz8(int row, int slot) {
    return (slot + (row & 7) + 2 * ((row >> 3) & 3)) & 7;
}

__global__ __launch_bounds__(256, 1)
void attn_mfma(const short* __restrict__ qr, const short* __restrict__ qi,
               const short* __restrict__ kr, const short* __restrict__ ki,
               const short* __restrict__ vtr, const short* __restrict__ vti,
               float* __restrict__ out)
{
    __shared__ short sK [2][2][64][64];   // [buf][comp][row][col (swizzled 16B slots)]
    __shared__ short sVt[2][2][64][64];

    const int tid = threadIdx.x;
    const int w = tid >> 6, l = tid & 63, lg = l >> 4, lc = l & 15;

    // XCD swizzle: 256 blocks, hw xcd = dlin % 8; 2 bh per XCD.
    const int dlin = blockIdx.y * 16 + blockIdx.x;   // [0, 256)
    const int xcd = dlin & 7, slot = dlin >> 3;      // slot in [0, 32)
    const int bh = xcd * 2 + (slot >> 4);
    const int qt = slot & 15;
    const int b = bh >> 3, h = bh & 7;

    // Q fragments (loop-invariant): wave w owns q-rows qt*128 + w*32 + qh*16 ..
    s16x8 Qr[2][2], Qi_[2][2], Qin[2][2];
#pragma unroll
    for (int qh = 0; qh < 2; ++qh) {
        size_t base = ((size_t)bh * N_ + (size_t)qt * 128 + w * 32 + qh * 16 + lc) * DK_ + lg * 8;
#pragma unroll
        for (int c = 0; c < 2; ++c) {
            Qr[qh][c]  = *(const s16x8*)&qr[base + c * 32];
            Qi_[qh][c] = *(const s16x8*)&qi[base + c * 32];
            Qin[qh][c] = Qi_[qh][c] ^ (short)0x8000;
        }
    }

    s16x8 onesf;
#pragma unroll
    for (int u = 0; u < 8; ++u) onesf[u] = (short)0x3F80;   // bf16 1.0

    fx4 o_re[2][4], o_im[2][4], o_l[2];
#pragma unroll
    for (int qh = 0; qh < 2; ++qh) {
#pragma unroll
        for (int dt = 0; dt < 4; ++dt)
#pragma unroll
            for (int j = 0; j < 4; ++j) { o_re[qh][dt][j] = 0.f; o_im[qh][dt][j] = 0.f; }
#pragma unroll
        for (int j = 0; j < 4; ++j) o_l[qh][j] = 0.f;
    }

    // permuted base row for QK A-operand; lane-invariant swizzle bases
    const int rS = ((lc >> 2) << 3) | (lc & 3);
    const int bqs = lg + (lc & 3) + 2 * (lc >> 2);   // QK read swizzle base (mod 8)
    const int bvs = lg + (lc & 7) + 2 * (lc >> 3);   // PV read swizzle base (mod 8)

    // staging: 256 threads, 16B each; thread covers rows srow and srow+32.
    const int srow = tid >> 3, cs = tid & 7;
    const int sw = swz8(srow, cs) * 8;               // same for srow and srow+32
    int koff = bh * (N_ * DK_) + srow * DK_ + cs * 8;   // += 64*DK_ per tile
    int voff = bh * (DK_ * N_) + srow * N_ + cs * 8;    // += 64 per tile

    s16x8 rgK[4], rgV[4];
    auto issue = [&]() {
        rgK[0] = *(const s16x8*)&kr [koff];
        rgK[1] = *(const s16x8*)&kr [koff + 32 * DK_];
        rgK[2] = *(const s16x8*)&ki [koff];
        rgK[3] = *(const s16x8*)&ki [koff + 32 * DK_];
        rgV[0] = *(const s16x8*)&vtr[voff];
        rgV[1] = *(const s16x8*)&vtr[voff + 32 * N_];
        rgV[2] = *(const s16x8*)&vti[voff];
        rgV[3] = *(const s16x8*)&vti[voff + 32 * N_];
        koff += 64 * DK_; voff += 64;
    };
    auto stage = [&](int bi) {
        *(s16x8*)&sK [bi][0][srow     ][sw] = rgK[0];
        *(s16x8*)&sK [bi][0][srow + 32][sw] = rgK[1];
        *(s16x8*)&sK [bi][1][srow     ][sw] = rgK[2];
        *(s16x8*)&sK [bi][1][srow + 32][sw] = rgK[3];
        *(s16x8*)&sVt[bi][0][srow     ][sw] = rgV[0];
        *(s16x8*)&sVt[bi][0][srow + 32][sw] = rgV[1];
        *(s16x8*)&sVt[bi][1][srow     ][sw] = rgV[2];
        *(s16x8*)&sVt[bi][1][srow + 32][sw] = rgV[3];
    };

    issue();
    stage(0);
    for (int kt = 0; kt < NT_; ++kt) {
        const int bi = kt & 1;
        __syncthreads();   // stage(bi) visible; all waves done reading buf bi (2 iters ago)
        if (kt + 1 < NT_) issue();   // T14 fire-and-forget: lands during compute

        // ---- QK^T, swapped + permuted tiles: lane ends with (per qh)
        //      tile t, reg j  ->  k = 8*lg + j + 4*(t&1) + 32*(t>>1), q = lc
        fx4 are[2][4], aim[2][4];
#pragma unroll
        for (int qh = 0; qh < 2; ++qh)
#pragma unroll
            for (int t = 0; t < 4; ++t)
#pragma unroll
                for (int j = 0; j < 4; ++j) { are[qh][t][j] = 0.f; aim[qh][t][j] = 0.f; }

        __builtin_amdgcn_s_setprio(1);
#pragma unroll
        for (int t = 0; t < 4; ++t) {
            const int row = rS + ((t & 1) << 2) + ((t >> 1) << 5);
#pragma unroll
            for (int c = 0; c < 2; ++c) {
                const int sl = ((bqs + 4 * ((c + t) & 1)) & 7) * 8;
                s16x8 Krf = *(const s16x8*)&sK[bi][0][row][sl];
                s16x8 Kif = *(const s16x8*)&sK[bi][1][row][sl];
#pragma unroll
                for (int qh = 0; qh < 2; ++qh) {
                    are[qh][t] = MFMA16(Krf, Qr[qh][c],  are[qh][t]);   // kr*qr
                    are[qh][t] = MFMA16(Kif, Qin[qh][c], are[qh][t]);   // -ki*qi
                    aim[qh][t] = MFMA16(Kif, Qr[qh][c],  aim[qh][t]);   // ki*qr
                    aim[qh][t] = MFMA16(Krf, Qi_[qh][c], aim[qh][t]);   // kr*qi
                }
            }
        }
        __builtin_amdgcn_s_setprio(0);

        // ---- p = 2^(C2*|dist| - M0); assemble PV A-fragments IN REGISTERS.
        s16x8 Pf[2][2];
#pragma unroll
        for (int qh = 0; qh < 2; ++qh) {
            ix4 w0, w1;
#pragma unroll
            for (int t = 0; t < 4; ++t) {
                float p[4];
#pragma unroll
                for (int j = 0; j < 4; ++j) {
                    float u2 = fmaf(are[qh][t][j], are[qh][t][j], aim[qh][t][j] * aim[qh][t][j]);
                    p[j] = fexp2(fmaf(C2_, fsqrt_(u2), -M0_));
                }
                int d0 = pack_tr(p[0], p[1]);
                int d1 = pack_tr(p[2], p[3]);
                if (t == 0)      { w0[0] = d0; w0[1] = d1; }
                else if (t == 1) { w0[2] = d0; w0[3] = d1; }
                else if (t == 2) { w1[0] = d0; w1[1] = d1; }
                else             { w1[2] = d0; w1[3] = d1; }
            }
            Pf[qh][0] = __builtin_bit_cast(s16x8, w0);
            Pf[qh][1] = __builtin_bit_cast(s16x8, w1);
        }

        // ---- PV + row-sum via ones-MFMA (V fragments shared across qh)
        __builtin_amdgcn_s_setprio(1);
#pragma unroll
        for (int qh = 0; qh < 2; ++qh) {
            o_l[qh] = MFMA16(Pf[qh][0], onesf, o_l[qh]);
            o_l[qh] = MFMA16(Pf[qh][1], onesf, o_l[qh]);
        }
#pragma unroll
        for (int dt = 0; dt < 4; ++dt) {
            const int d = dt * 16 + lc;
            const int s0 = ((bvs + 4 * dt) & 7) * 8;
            const int s1 = ((bvs + 4 * dt + 4) & 7) * 8;
            s16x8 Vr0 = *(const s16x8*)&sVt[bi][0][d][s0];
            s16x8 Vi0 = *(const s16x8*)&sVt[bi][1][d][s0];
            s16x8 Vr1 = *(const s16x8*)&sVt[bi][0][d][s1];
            s16x8 Vi1 = *(const s16x8*)&sVt[bi][1][d][s1];
#pragma unroll
            for (int qh = 0; qh < 2; ++qh) {
                o_re[qh][dt] = MFMA16(Pf[qh][0], Vr0, o_re[qh][dt]);
                o_im[qh][dt] = MFMA16(Pf[qh][0], Vi0, o_im[qh][dt]);
                o_re[qh][dt] = MFMA16(Pf[qh][1], Vr1, o_re[qh][dt]);
                o_im[qh][dt] = MFMA16(Pf[qh][1], Vi1, o_im[qh][dt]);
            }
        }
        __builtin_amdgcn_s_setprio(0);

        if (kt + 1 < NT_) stage((kt + 1) & 1);   // writes other buffer: no barrier needed here
    }

    float2* po = (float2*)out;
#pragma unroll
    for (int qh = 0; qh < 2; ++qh) {
        float inv[4];
#pragma unroll
        for (int j = 0; j < 4; ++j) inv[j] = 1.f / o_l[qh][j];
#pragma unroll
        for (int dt = 0; dt < 4; ++dt)
#pragma unroll
            for (int j = 0; j < 4; ++j) {
                int n  = qt * 128 + w * 32 + qh * 16 + lg * 4 + j;
                int dg = h * 64 + dt * 16 + lc;
                po[((size_t)b * N_ + n) * D_ + dg] =
                    make_float2(o_re[qh][dt][j] * inv[j], o_im[qh][dt][j] * inv[j]);
            }
    }
}

// ---------------------------------------------------------------------------
extern "C" void kernel_launch(void* const* d_in, const int* in_sizes, int n_in,
                              void* d_out, int out_size, void* d_ws, size_t ws_size,
                              hipStream_t stream)
{
    const float* xr = (const float*)d_in[0];
    const float* xi = (const float*)d_in[1];
    const float* Wq_r = (const float*)d_in[2];
    const float* Wq_i = (const float*)d_in[3];
    const float* bq_r = (const float*)d_in[4];
    const float* bq_i = (const float*)d_in[5];
    const float* Wk_r = (const float*)d_in[6];
    const float* Wk_i = (const float*)d_in[7];
    const float* bk_r = (const float*)d_in[8];
    const float* bk_i = (const float*)d_in[9];
    const float* Wv_r = (const float*)d_in[10];
    const float* Wv_i = (const float*)d_in[11];
    const float* bv_r = (const float*)d_in[12];
    const float* bv_i = (const float*)d_in[13];

    short* ws = (short*)d_ws;
    const size_t SZ = (size_t)B_ * H_ * N_ * DK_;
    short* qr_  = ws + 0 * SZ;
    short* qi_  = ws + 1 * SZ;
    short* kr_  = ws + 2 * SZ;
    short* ki_  = ws + 3 * SZ;
    short* vtr_ = ws + 4 * SZ;
    short* vti_ = ws + 5 * SZ;

    dim3 qkgrid(D_ / 64, M_ / 128, 2);   // 8 x 32 x 2
    qkproj_mfma<<<qkgrid, 256, 0, stream>>>(xr, xi,
                                            Wq_r, Wq_i, bq_r, bq_i,
                                            Wk_r, Wk_i, bk_r, bk_i,
                                            qr_, qi_, kr_, ki_);
    dim3 vgrid(D_ / 64, M_ / 64);        // 8 x 64 = 512 blocks
    vproj_mfma<<<vgrid, 256, 0, stream>>>(xr, xi, Wv_r, Wv_i, bv_r, bv_i, vtr_, vti_);

    dim3 agrid(16, 16);                  // 256 blocks, 256 threads, 1 block/CU
    attn_mfma<<<agrid, 256, 0, stream>>>(qr_, qi_, kr_, ki_, vtr_, vti_, (float*)d_out);
}

// Round 3
// 120.562 us; speedup vs baseline: 1.1351x; 1.1351x over previous
//
#include <hip/hip_runtime.h>
#include <hip/hip_bf16.h>
#include <math.h>

#define B_ 2
#define N_ 2048
#define D_ 512
#define H_ 8
#define DK_ 64
#define M_ (B_ * N_)  // 4096

typedef short s16x8 __attribute__((ext_vector_type(8)));
typedef short s16x4 __attribute__((ext_vector_type(4)));
typedef float fx4   __attribute__((ext_vector_type(4)));
typedef int   ix4   __attribute__((ext_vector_type(4)));

static __device__ __forceinline__ short f2bf(float f) {
    __hip_bfloat16 h = __float2bfloat16(f);
    return __builtin_bit_cast(short, h);
}
static __device__ __forceinline__ float bf2f(short s) {
    unsigned int u = ((unsigned int)(unsigned short)s) << 16;
    return __builtin_bit_cast(float, u);
}
static __device__ __forceinline__ float fexp2(float x) {
#if __has_builtin(__builtin_amdgcn_exp2f)
    return __builtin_amdgcn_exp2f(x);
#else
    return exp2f(x);
#endif
}
static __device__ __forceinline__ float fsqrt_(float x) {
#if __has_builtin(__builtin_amdgcn_sqrtf)
    return __builtin_amdgcn_sqrtf(x);
#else
    return sqrtf(x);
#endif
}
// pack two f32 into bf16x2 by truncation (valid for p >= 0): lo = a, hi = b.
static __device__ __forceinline__ int pack_tr(float a, float b) {
    unsigned ua = __builtin_bit_cast(unsigned, a);
    unsigned ub = __builtin_bit_cast(unsigned, b);
    return (int)((ua >> 16) | (ub & 0xFFFF0000u));
}

#define MFMA16(a, b, c) __builtin_amdgcn_mfma_f32_16x16x32_bf16(a, b, c, 0, 0, 0)

// log2-units score scale: 0.125 * log2(e); fixed softmax shift M0 (shift-invariant)
#define C2_ 0.18033688f
#define M0_ 16.0f

// ---------------------------------------------------------------------------
// Q+K projection (one dispatch, z selects weights/outputs). bf16 MFMA.
// Tile 128x64, BK=32, 4 waves (2x2). T14 reg-staged prefetch, incremental addr.
// ---------------------------------------------------------------------------
__global__ __launch_bounds__(256, 2)
void qkproj_mfma(const float* __restrict__ xr, const float* __restrict__ xi,
                 const float* __restrict__ W0r, const float* __restrict__ W0i,
                 const float* __restrict__ b0r, const float* __restrict__ b0i,
                 const float* __restrict__ W1r, const float* __restrict__ W1i,
                 const float* __restrict__ b1r, const float* __restrict__ b1i,
                 short* __restrict__ o0r, short* __restrict__ o0i,
                 short* __restrict__ o1r, short* __restrict__ o1i)
{
    __shared__ short sA[2][128][40];
    __shared__ short sB[2][64][40];

    const int tid = threadIdx.x;
    const int w = tid >> 6, l = tid & 63, lg = l >> 4, lc = l & 15;
    const int wr = w >> 1, wc = w & 1;
    const int bn = blockIdx.x, bm = blockIdx.y, z = blockIdx.z;
    const float* Wr = z ? W1r : W0r;
    const float* Wi = z ? W1i : W0i;
    const float* br = z ? b1r : b0r;
    const float* bi = z ? b1i : b0i;
    short* outr = z ? o1r : o0r;
    short* outi = z ? o1i : o0i;

    const int srow = tid >> 3, scol = (tid & 7) * 4;
    int aoff = (bm * 128 + srow) * D_ + scol;   // += 32 per k-step
    int boff = (bn * 64 + srow) * D_ + scol;

    float4 rA[8], rB[4];
    auto issue = [&]() {
#pragma unroll
        for (int u = 0; u < 8; ++u) {
            const float* src = (u >= 4) ? xi : xr;
            rA[u] = *(const float4*)&src[aoff + (u & 3) * 32 * D_];
        }
#pragma unroll
        for (int u = 0; u < 4; ++u) {
            const float* src = (u >= 2) ? Wi : Wr;
            rB[u] = *(const float4*)&src[boff + (u & 1) * 32 * D_];
        }
        aoff += 32; boff += 32;
    };

    fx4 Cre[4][2], Cim[4][2];
#pragma unroll
    for (int mf = 0; mf < 4; ++mf)
#pragma unroll
        for (int nf = 0; nf < 2; ++nf)
#pragma unroll
            for (int j = 0; j < 4; ++j) { Cre[mf][nf][j] = 0.f; Cim[mf][nf][j] = 0.f; }

    issue();
    for (int k0 = 0; k0 < D_; k0 += 32) {
        __syncthreads();
#pragma unroll
        for (int u = 0; u < 8; ++u) {
            int comp = u >> 2, row = (u & 3) * 32 + srow;
            float vv[4] = {rA[u].x, rA[u].y, rA[u].z, rA[u].w};
            s16x4 hv;
#pragma unroll
            for (int q = 0; q < 4; ++q) hv[q] = f2bf(vv[q]);
            *(s16x4*)&sA[comp][row][scol] = hv;
        }
#pragma unroll
        for (int u = 0; u < 4; ++u) {
            int comp = u >> 1, row = (u & 1) * 32 + srow;
            float vv[4] = {rB[u].x, rB[u].y, rB[u].z, rB[u].w};
            s16x4 hv;
#pragma unroll
            for (int q = 0; q < 4; ++q) hv[q] = f2bf(vv[q]);
            *(s16x4*)&sB[comp][row][scol] = hv;
        }
        __syncthreads();
        if (k0 + 32 < D_) issue();

        s16x8 a[2][4];
#pragma unroll
        for (int comp = 0; comp < 2; ++comp)
#pragma unroll
            for (int mf = 0; mf < 4; ++mf)
                a[comp][mf] = *(const s16x8*)&sA[comp][wr * 64 + mf * 16 + lc][lg * 8];
        s16x8 bfr[2][2], bin[2];
#pragma unroll
        for (int comp = 0; comp < 2; ++comp)
#pragma unroll
            for (int nf = 0; nf < 2; ++nf)
                bfr[comp][nf] = *(const s16x8*)&sB[comp][wc * 32 + nf * 16 + lc][lg * 8];
#pragma unroll
        for (int nf = 0; nf < 2; ++nf) bin[nf] = bfr[1][nf] ^ (short)0x8000;

        __builtin_amdgcn_s_setprio(1);
#pragma unroll
        for (int mf = 0; mf < 4; ++mf)
#pragma unroll
            for (int nf = 0; nf < 2; ++nf) {
                Cre[mf][nf] = MFMA16(a[0][mf], bfr[0][nf], Cre[mf][nf]);
                Cre[mf][nf] = MFMA16(a[1][mf], bin[nf],    Cre[mf][nf]);
                Cim[mf][nf] = MFMA16(a[0][mf], bfr[1][nf], Cim[mf][nf]);
                Cim[mf][nf] = MFMA16(a[1][mf], bfr[0][nf], Cim[mf][nf]);
            }
        __builtin_amdgcn_s_setprio(0);
    }

    const int bb = (bm * 128) >> 11;
#pragma unroll
    for (int nf = 0; nf < 2; ++nf) {
        const int c = bn * 64 + wc * 32 + nf * 16 + lc;
        const float brv = br[c], biv = bi[c];
        const int h = c >> 6, dd = c & 63;
        const int n00 = (bm * 128 + wr * 64 + lg * 4) & (N_ - 1);
        size_t obase = (((size_t)(bb * H_ + h) * N_) + n00) * DK_ + dd;
#pragma unroll
        for (int mf = 0; mf < 4; ++mf)
#pragma unroll
            for (int j = 0; j < 4; ++j) {
                size_t o = obase + (size_t)(mf * 16 + j) * DK_;
                outr[o] = f2bf(Cre[mf][nf][j] + brv);
                outi[o] = f2bf(Cim[mf][nf][j] + biv);
            }
    }
}

// ---------------------------------------------------------------------------
// V projection: 3-term bf16 split (hi/lo), transposed output [bh][dk][n].
// BM=64 (grid 512 -> 2 blocks/CU). Wave tile 32x32.
// ---------------------------------------------------------------------------
__global__ __launch_bounds__(256, 2)
void vproj_mfma(const float* __restrict__ xr, const float* __restrict__ xi,
                const float* __restrict__ Wr, const float* __restrict__ Wi,
                const float* __restrict__ br, const float* __restrict__ bi,
                short* __restrict__ outr, short* __restrict__ outi)
{
    __shared__ short sA[2][2][64][40];
    __shared__ short sB[2][2][64][40];

    const int tid = threadIdx.x;
    const int w = tid >> 6, l = tid & 63, lg = l >> 4, lc = l & 15;
    const int wr = w >> 1, wc = w & 1;
    const int bn = blockIdx.x, bm = blockIdx.y;

    const int srow = tid >> 3, scol = (tid & 7) * 4;
    int aoff = (bm * 64 + srow) * D_ + scol;
    int boff = (bn * 64 + srow) * D_ + scol;

    float4 rA[4], rB[4];
    auto issue = [&]() {
#pragma unroll
        for (int u = 0; u < 4; ++u) {
            const float* src = (u >= 2) ? xi : xr;
            rA[u] = *(const float4*)&src[aoff + (u & 1) * 32 * D_];
        }
#pragma unroll
        for (int u = 0; u < 4; ++u) {
            const float* src = (u >= 2) ? Wi : Wr;
            rB[u] = *(const float4*)&src[boff + (u & 1) * 32 * D_];
        }
        aoff += 32; boff += 32;
    };

    fx4 Cre[2][2], Cim[2][2];
#pragma unroll
    for (int mf = 0; mf < 2; ++mf)
#pragma unroll
        for (int nf = 0; nf < 2; ++nf)
#pragma unroll
            for (int j = 0; j < 4; ++j) { Cre[mf][nf][j] = 0.f; Cim[mf][nf][j] = 0.f; }

    issue();
    for (int k0 = 0; k0 < D_; k0 += 32) {
        __syncthreads();
#pragma unroll
        for (int u = 0; u < 4; ++u) {
            int comp = u >> 1, row = (u & 1) * 32 + srow;
            float vv[4] = {rA[u].x, rA[u].y, rA[u].z, rA[u].w};
            s16x4 hv, lv;
#pragma unroll
            for (int q = 0; q < 4; ++q) {
                short hh = f2bf(vv[q]);
                hv[q] = hh;
                lv[q] = f2bf(vv[q] - bf2f(hh));
            }
            *(s16x4*)&sA[comp][0][row][scol] = hv;
            *(s16x4*)&sA[comp][1][row][scol] = lv;
        }
#pragma unroll
        for (int u = 0; u < 4; ++u) {
            int comp = u >> 1, row = (u & 1) * 32 + srow;
            float vv[4] = {rB[u].x, rB[u].y, rB[u].z, rB[u].w};
            s16x4 hv, lv;
#pragma unroll
            for (int q = 0; q < 4; ++q) {
                short hh = f2bf(vv[q]);
                hv[q] = hh;
                lv[q] = f2bf(vv[q] - bf2f(hh));
            }
            *(s16x4*)&sB[comp][0][row][scol] = hv;
            *(s16x4*)&sB[comp][1][row][scol] = lv;
        }
        __syncthreads();
        if (k0 + 32 < D_) issue();

        s16x8 a[2][2][2];
#pragma unroll
        for (int comp = 0; comp < 2; ++comp)
#pragma unroll
            for (int s = 0; s < 2; ++s)
#pragma unroll
                for (int mf = 0; mf < 2; ++mf)
                    a[comp][s][mf] = *(const s16x8*)&sA[comp][s][wr * 32 + mf * 16 + lc][lg * 8];
        s16x8 bfr[2][2][2], bin[2][2];
#pragma unroll
        for (int comp = 0; comp < 2; ++comp)
#pragma unroll
            for (int s = 0; s < 2; ++s)
#pragma unroll
                for (int nf = 0; nf < 2; ++nf)
                    bfr[comp][s][nf] = *(const s16x8*)&sB[comp][s][wc * 32 + nf * 16 + lc][lg * 8];
#pragma unroll
        for (int s = 0; s < 2; ++s)
#pragma unroll
            for (int nf = 0; nf < 2; ++nf)
                bin[s][nf] = bfr[1][s][nf] ^ (short)0x8000;

        __builtin_amdgcn_s_setprio(1);
#pragma unroll
        for (int mf = 0; mf < 2; ++mf)
#pragma unroll
            for (int nf = 0; nf < 2; ++nf) {
                fx4 cr = Cre[mf][nf], ci = Cim[mf][nf];
                cr = MFMA16(a[0][0][mf], bfr[0][0][nf], cr);
                cr = MFMA16(a[1][0][mf], bin[0][nf],    cr);
                ci = MFMA16(a[0][0][mf], bfr[1][0][nf], ci);
                ci = MFMA16(a[1][0][mf], bfr[0][0][nf], ci);
                cr = MFMA16(a[0][0][mf], bfr[0][1][nf], cr);
                cr = MFMA16(a[0][1][mf], bfr[0][0][nf], cr);
                cr = MFMA16(a[1][0][mf], bin[1][nf],    cr);
                cr = MFMA16(a[1][1][mf], bin[0][nf],    cr);
                ci = MFMA16(a[0][0][mf], bfr[1][1][nf], ci);
                ci = MFMA16(a[0][1][mf], bfr[1][0][nf], ci);
                ci = MFMA16(a[1][0][mf], bfr[0][1][nf], ci);
                ci = MFMA16(a[1][1][mf], bfr[0][0][nf], ci);
                Cre[mf][nf] = cr; Cim[mf][nf] = ci;
            }
        __builtin_amdgcn_s_setprio(0);
    }

    const int bb = (bm * 64) >> 11;
#pragma unroll
    for (int nf = 0; nf < 2; ++nf) {
        const int c = bn * 64 + wc * 32 + nf * 16 + lc;
        const float brv = br[c], biv = bi[c];
        const int h = c >> 6, dd = c & 63;
#pragma unroll
        for (int mf = 0; mf < 2; ++mf) {
            int m0 = bm * 64 + wr * 32 + mf * 16 + lg * 4;
            int n0 = m0 & (N_ - 1);
            s16x4 pr, pi;
#pragma unroll
            for (int j = 0; j < 4; ++j) {
                pr[j] = f2bf(Cre[mf][nf][j] + brv);
                pi[j] = f2bf(Cim[mf][nf][j] + biv);
            }
            size_t o = (((size_t)(bb * H_ + h) * DK_) + dd) * N_ + n0;
            *(s16x4*)&outr[o] = pr;
            *(s16x4*)&outi[o] = pi;
        }
    }
}

// ---------------------------------------------------------------------------
// MFMA flash attention, QBLK=128, split-K=2.
// 512 threads = 4 q-waves x 2 k-groups; group g computes tiles 2r+g.
// Restores 8 waves/CU (round-2 lesson: perf tracks waves/CU) while KEEPING
// the halved LDS-read traffic (K/V fragments shared across qh=2 Q-halves).
// Fixed-shift softmax (M0) => split-K partials are directly addable; cheap
// LDS merge in the epilogue, no rescaling.
// Double-buffered LDS (128 KB), ONE barrier per round; per-wave inner body
// is the round-2 verified code (same rotation swizzle, permuted K rows).
// XCD remap: 2 bh per XCD -> K/V resident in that XCD's L2.
// ---------------------------------------------------------------------------
#define NT_ (N_ / 64)    // 32 tiles
#define NR_ (NT_ / 2)    // 16 rounds (2 tiles per round)

static __device__ __forceinline__ int swz8(int row, int slot) {
    return (slot + (row & 7) + 2 * ((row >> 3) & 3)) & 7;
}

__global__ __launch_bounds__(512, 2)
void attn_mfma(const short* __restrict__ qr, const short* __restrict__ qi,
               const short* __restrict__ kr, const short* __restrict__ ki,
               const short* __restrict__ vtr, const short* __restrict__ vti,
               float* __restrict__ out)
{
    __shared__ short sK [2][2][2][64][64];   // [dbuf][kgroup][comp][row][swizzled]
    __shared__ short sVt[2][2][2][64][64];

    const int tid = threadIdx.x;
    const int w = tid >> 6, l = tid & 63, lg = l >> 4, lc = l & 15;
    const int kg = w & 1, qw = w >> 1;       // k-group, q-wave

    // XCD swizzle: 256 blocks, hw xcd = dlin % 8; 2 bh per XCD.
    const int dlin = blockIdx.y * 16 + blockIdx.x;   // [0, 256)
    const int xcd = dlin & 7, slot = dlin >> 3;      // slot in [0, 32)
    const int bh = xcd * 2 + (slot >> 4);
    const int qt = slot & 15;
    const int b = bh >> 3, h = bh & 7;

    // Q fragments (loop-invariant): q-wave qw owns rows qt*128 + qw*32 + qh*16 ..
    s16x8 Qr[2][2], Qi_[2][2], Qin[2][2];
#pragma unroll
    for (int qh = 0; qh < 2; ++qh) {
        size_t base = ((size_t)bh * N_ + (size_t)qt * 128 + qw * 32 + qh * 16 + lc) * DK_ + lg * 8;
#pragma unroll
        for (int c = 0; c < 2; ++c) {
            Qr[qh][c]  = *(const s16x8*)&qr[base + c * 32];
            Qi_[qh][c] = *(const s16x8*)&qi[base + c * 32];
            Qin[qh][c] = Qi_[qh][c] ^ (short)0x8000;
        }
    }

    s16x8 onesf;
#pragma unroll
    for (int u = 0; u < 8; ++u) onesf[u] = (short)0x3F80;   // bf16 1.0

    fx4 o_re[2][4], o_im[2][4], o_l[2];
#pragma unroll
    for (int qh = 0; qh < 2; ++qh) {
#pragma unroll
        for (int dt = 0; dt < 4; ++dt)
#pragma unroll
            for (int j = 0; j < 4; ++j) { o_re[qh][dt][j] = 0.f; o_im[qh][dt][j] = 0.f; }
#pragma unroll
        for (int j = 0; j < 4; ++j) o_l[qh][j] = 0.f;
    }

    // permuted base row for QK A-operand; lane-invariant swizzle bases
    const int rS = ((lc >> 2) << 3) | (lc & 3);
    const int bqs = lg + (lc & 3) + 2 * (lc >> 2);   // QK read swizzle base (mod 8)
    const int bvs = lg + (lc & 7) + 2 * (lc >> 3);   // PV read swizzle base (mod 8)

    // staging: 512 threads x 16B cover one 64x64 plane; 8 planes (2kg x 2comp x K,V)
    const int srow = tid >> 3, cs = tid & 7;         // srow in [0,64)
    const int sw = swz8(srow, cs) * 8;
    int koff = bh * (N_ * DK_) + srow * DK_ + cs * 8;   // += 128*DK_ per round
    int voff = bh * (DK_ * N_) + srow * N_ + cs * 8;    // += 128 per round

    s16x8 rgK[2][2], rgV[2][2];
    auto issue = [&]() {
#pragma unroll
        for (int g = 0; g < 2; ++g) {
            rgK[g][0] = *(const s16x8*)&kr [koff + g * 64 * DK_];
            rgK[g][1] = *(const s16x8*)&ki [koff + g * 64 * DK_];
            rgV[g][0] = *(const s16x8*)&vtr[voff + g * 64];
            rgV[g][1] = *(const s16x8*)&vti[voff + g * 64];
        }
        koff += 128 * DK_; voff += 128;
    };
    auto stage = [&](int nb) {
#pragma unroll
        for (int g = 0; g < 2; ++g)
#pragma unroll
            for (int comp = 0; comp < 2; ++comp) {
                *(s16x8*)&sK [nb][g][comp][srow][sw] = rgK[g][comp];
                *(s16x8*)&sVt[nb][g][comp][srow][sw] = rgV[g][comp];
            }
    };

    issue();
    stage(0);
    for (int r = 0; r < NR_; ++r) {
        const int cb = r & 1;
        __syncthreads();   // stage(cb) visible; all waves done reading cb^1
        if (r + 1 < NR_) issue();   // T14 fire-and-forget: lands during compute

        // ---- QK^T, swapped + permuted tiles: lane ends with (per qh)
        //      tile t, reg j  ->  k = 8*lg + j + 4*(t&1) + 32*(t>>1), q = lc
        fx4 are[2][4], aim[2][4];
#pragma unroll
        for (int qh = 0; qh < 2; ++qh)
#pragma unroll
            for (int t = 0; t < 4; ++t)
#pragma unroll
                for (int j = 0; j < 4; ++j) { are[qh][t][j] = 0.f; aim[qh][t][j] = 0.f; }

        __builtin_amdgcn_s_setprio(1);
#pragma unroll
        for (int t = 0; t < 4; ++t) {
            const int row = rS + ((t & 1) << 2) + ((t >> 1) << 5);
#pragma unroll
            for (int c = 0; c < 2; ++c) {
                const int sl = ((bqs + 4 * ((c + t) & 1)) & 7) * 8;
                s16x8 Krf = *(const s16x8*)&sK[cb][kg][0][row][sl];
                s16x8 Kif = *(const s16x8*)&sK[cb][kg][1][row][sl];
#pragma unroll
                for (int qh = 0; qh < 2; ++qh) {
                    are[qh][t] = MFMA16(Krf, Qr[qh][c],  are[qh][t]);   // kr*qr
                    are[qh][t] = MFMA16(Kif, Qin[qh][c], are[qh][t]);   // -ki*qi
                    aim[qh][t] = MFMA16(Kif, Qr[qh][c],  aim[qh][t]);   // ki*qr
                    aim[qh][t] = MFMA16(Krf, Qi_[qh][c], aim[qh][t]);   // kr*qi
                }
            }
        }
        __builtin_amdgcn_s_setprio(0);

        // ---- p = 2^(C2*|dist| - M0); assemble PV A-fragments IN REGISTERS.
        s16x8 Pf[2][2];
#pragma unroll
        for (int qh = 0; qh < 2; ++qh) {
            ix4 w0, w1;
#pragma unroll
            for (int t = 0; t < 4; ++t) {
                float p[4];
#pragma unroll
                for (int j = 0; j < 4; ++j) {
                    float u2 = fmaf(are[qh][t][j], are[qh][t][j], aim[qh][t][j] * aim[qh][t][j]);
                    p[j] = fexp2(fmaf(C2_, fsqrt_(u2), -M0_));
                }
                int d0 = pack_tr(p[0], p[1]);
                int d1 = pack_tr(p[2], p[3]);
                if (t == 0)      { w0[0] = d0; w0[1] = d1; }
                else if (t == 1) { w0[2] = d0; w0[3] = d1; }
                else if (t == 2) { w1[0] = d0; w1[1] = d1; }
                else             { w1[2] = d0; w1[3] = d1; }
            }
            Pf[qh][0] = __builtin_bit_cast(s16x8, w0);
            Pf[qh][1] = __builtin_bit_cast(s16x8, w1);
        }

        // ---- PV + row-sum via ones-MFMA (V fragments shared across qh)
        __builtin_amdgcn_s_setprio(1);
#pragma unroll
        for (int qh = 0; qh < 2; ++qh) {
            o_l[qh] = MFMA16(Pf[qh][0], onesf, o_l[qh]);
            o_l[qh] = MFMA16(Pf[qh][1], onesf, o_l[qh]);
        }
#pragma unroll
        for (int dt = 0; dt < 4; ++dt) {
            const int d = dt * 16 + lc;
            const int s0 = ((bvs + 4 * dt) & 7) * 8;
            const int s1 = ((bvs + 4 * dt + 4) & 7) * 8;
            s16x8 Vr0 = *(const s16x8*)&sVt[cb][kg][0][d][s0];
            s16x8 Vi0 = *(const s16x8*)&sVt[cb][kg][1][d][s0];
            s16x8 Vr1 = *(const s16x8*)&sVt[cb][kg][0][d][s1];
            s16x8 Vi1 = *(const s16x8*)&sVt[cb][kg][1][d][s1];
#pragma unroll
            for (int qh = 0; qh < 2; ++qh) {
                o_re[qh][dt] = MFMA16(Pf[qh][0], Vr0, o_re[qh][dt]);
                o_im[qh][dt] = MFMA16(Pf[qh][0], Vi0, o_im[qh][dt]);
                o_re[qh][dt] = MFMA16(Pf[qh][1], Vr1, o_re[qh][dt]);
                o_im[qh][dt] = MFMA16(Pf[qh][1], Vi1, o_im[qh][dt]);
            }
        }
        __builtin_amdgcn_s_setprio(0);

        if (r + 1 < NR_) stage(cb ^ 1);   // other buffer; top-of-loop barrier protects
    }

    // ---- split-K merge: kg=1 publishes partials, kg=0 adds + writes.
    // stride 37 floats: lane stride 37 -> bank step 5 (invertible mod 32),
    // 2-way max = free. Buffer 4*64*37*4B = 37.9 KB, aliased onto sK.
    float* red = (float*)&sK[0][0][0][0][0];
    float2* po = (float2*)out;
#pragma unroll
    for (int qh = 0; qh < 2; ++qh) {
        __syncthreads();
        if (kg == 1) {
            const int base = (qw * 64 + l) * 37;
#pragma unroll
            for (int dt = 0; dt < 4; ++dt)
#pragma unroll
                for (int j = 0; j < 4; ++j) {
                    red[base + dt * 8 + j * 2 + 0] = o_re[qh][dt][j];
                    red[base + dt * 8 + j * 2 + 1] = o_im[qh][dt][j];
                }
#pragma unroll
            for (int j = 0; j < 4; ++j) red[base + 32 + j] = o_l[qh][j];
        }
        __syncthreads();
        if (kg == 0) {
            const int base = (qw * 64 + l) * 37;
            float inv[4];
#pragma unroll
            for (int j = 0; j < 4; ++j)
                inv[j] = 1.f / (o_l[qh][j] + red[base + 32 + j]);
#pragma unroll
            for (int dt = 0; dt < 4; ++dt)
#pragma unroll
                for (int j = 0; j < 4; ++j) {
                    float re = o_re[qh][dt][j] + red[base + dt * 8 + j * 2 + 0];
                    float im = o_im[qh][dt][j] + red[base + dt * 8 + j * 2 + 1];
                    int n  = qt * 128 + qw * 32 + qh * 16 + lg * 4 + j;
                    int dg = h * 64 + dt * 16 + lc;
                    po[((size_t)b * N_ + n) * D_ + dg] =
                        make_float2(re * inv[j], im * inv[j]);
                }
        }
    }
}

// ---------------------------------------------------------------------------
extern "C" void kernel_launch(void* const* d_in, const int* in_sizes, int n_in,
                              void* d_out, int out_size, void* d_ws, size_t ws_size,
                              hipStream_t stream)
{
    const float* xr = (const float*)d_in[0];
    const float* xi = (const float*)d_in[1];
    const float* Wq_r = (const float*)d_in[2];
    const float* Wq_i = (const float*)d_in[3];
    const float* bq_r = (const float*)d_in[4];
    const float* bq_i = (const float*)d_in[5];
    const float* Wk_r = (const float*)d_in[6];
    const float* Wk_i = (const float*)d_in[7];
    const float* bk_r = (const float*)d_in[8];
    const float* bk_i = (const float*)d_in[9];
    const float* Wv_r = (const float*)d_in[10];
    const float* Wv_i = (const float*)d_in[11];
    const float* bv_r = (const float*)d_in[12];
    const float* bv_i = (const float*)d_in[13];

    short* ws = (short*)d_ws;
    const size_t SZ = (size_t)B_ * H_ * N_ * DK_;
    short* qr_  = ws + 0 * SZ;
    short* qi_  = ws + 1 * SZ;
    short* kr_  = ws + 2 * SZ;
    short* ki_  = ws + 3 * SZ;
    short* vtr_ = ws + 4 * SZ;
    short* vti_ = ws + 5 * SZ;

    dim3 qkgrid(D_ / 64, M_ / 128, 2);   // 8 x 32 x 2
    qkproj_mfma<<<qkgrid, 256, 0, stream>>>(xr, xi,
                                            Wq_r, Wq_i, bq_r, bq_i,
                                            Wk_r, Wk_i, bk_r, bk_i,
                                            qr_, qi_, kr_, ki_);
    dim3 vgrid(D_ / 64, M_ / 64);        // 8 x 64 = 512 blocks
    vproj_mfma<<<vgrid, 256, 0, stream>>>(xr, xi, Wv_r, Wv_i, bv_r, bv_i, vtr_, vti_);

    dim3 agrid(16, 16);                  // 256 blocks, 512 threads, 1 block/CU
    attn_mfma<<<agrid, 512, 0, stream>>>(qr_, qi_, kr_, ki_, vtr_, vti_, (float*)d_out);
}